// Round 2
// baseline (3823.994 us; speedup 1.0000x reference)
//
#include <hip/hip_runtime.h>
#include <cstdint>

// ---------------------------------------------------------------------------
// RGCN (flight/airport heterograph).
// bf16 activation storage, fp32 compute. Per layer, per node type:
//   A = [agg_relA | agg_relB | x]  (K=768, bf16, chunked)
//   h = A @ [W_a; W_b; root] + bias   (single GEMM, no accumulation)
//   x = leaky(LN(h)) + x
// CSR built on-device once per call (count -> scan -> fill).
// Workspace: ~115 MB fixed + adaptive chunk buffer (fits ws_size).
// ---------------------------------------------------------------------------

namespace {

constexpr int kNF = 100000;
constexpr int kNA = 4000;
constexpr int kN  = 104000;
constexpr int kH  = 256;
constexpr int kL  = 4;
constexpr int kB  = 3;
constexpr int kEFA = 200000;
constexpr int kEAF = 200000;
constexpr int kEFF = 400000;
constexpr int kEAA = 40000;
constexpr int kETOT = 840000;
constexpr int kK = 768;  // concat K: 2 agg slots + x
// segment space (concatenated per-relation dst ranges):
// r0 fa->airport [0,kNA) | r1 af->flight [kNA,kNA+kNF)
// r2 ff->flight [kNA+kNF, kNA+2kNF) | r3 aa->airport [kNA+2kNF, kSEG)
constexpr int kSEG = 2 * kNA + 2 * kNF;           // 208000
constexpr int kScanBlocks = (kSEG + 1023) / 1024; // 204

__device__ __forceinline__ float b2f(unsigned short u) {
  union { unsigned int i; float f; } v;
  v.i = ((unsigned int)u) << 16;
  return v.f;
}
__device__ __forceinline__ unsigned short f2b(float f) {
  union { float f; unsigned int i; } v;
  v.f = f;
  unsigned int x = v.i;
  x += 0x7fffu + ((x >> 16) & 1u);  // round-to-nearest-even
  return (unsigned short)(x >> 16);
}

// ---------------------------------------------------------------------------
// Encoders: xout[rowoff+i] = xin[i] @ W + bias   (W [KIN][256]), bf16 out
// ---------------------------------------------------------------------------
template <int KIN>
__global__ __launch_bounds__(256) void k_encoder(
    const float* __restrict__ xin, const float* __restrict__ W,
    const float* __restrict__ bias, unsigned short* __restrict__ xout, int M,
    int rowoff) {
  __shared__ float xs[32][KIN];
  const int tid = threadIdx.x;
  const int r0 = blockIdx.x * 32;
  constexpr int TOT = 32 * KIN;
  for (int idx = tid * 4; idx < TOT; idx += 256 * 4) {
    const int rr = idx / KIN;
    const int kk = idx % KIN;
    *(float4*)&xs[rr][kk] = *(const float4*)&xin[(size_t)(r0 + rr) * KIN + kk];
  }
  __syncthreads();
  float acc[32];
#pragma unroll
  for (int i = 0; i < 32; ++i) acc[i] = 0.f;
  for (int k = 0; k < KIN; ++k) {
    const float wk = W[k * kH + tid];
#pragma unroll
    for (int i = 0; i < 32; ++i) acc[i] += xs[i][k] * wk;
  }
  const float bb = bias[tid];
#pragma unroll
  for (int i = 0; i < 32; ++i) {
    const int r = r0 + i;
    if (r < M) xout[(size_t)(rowoff + r) * kH + tid] = f2b(acc[i] + bb);
  }
}

// ---------------------------------------------------------------------------
// CSR build
// ---------------------------------------------------------------------------
__global__ void k_count(const int* __restrict__ ei, int E, int segbase,
                        int* __restrict__ cnt) {
  const int i = blockIdx.x * 256 + threadIdx.x;
  if (i < E) atomicAdd(&cnt[segbase + ei[E + i]], 1);
}

__global__ void k_scan1(const int* __restrict__ cnt, int* __restrict__ out,
                        int* __restrict__ bsum) {
  __shared__ int sh[256];
  const int tid = threadIdx.x;
  const int base = blockIdx.x * 1024 + tid * 4;
  int v[4];
#pragma unroll
  for (int j = 0; j < 4; ++j) v[j] = (base + j < kSEG) ? cnt[base + j] : 0;
  const int tsum = v[0] + v[1] + v[2] + v[3];
  sh[tid] = tsum;
  __syncthreads();
  for (int o = 1; o < 256; o <<= 1) {
    int t = (tid >= o) ? sh[tid - o] : 0;
    __syncthreads();
    sh[tid] += t;
    __syncthreads();
  }
  const int excl = sh[tid] - tsum;
  int run = excl;
#pragma unroll
  for (int j = 0; j < 4; ++j) {
    if (base + j < kSEG) out[base + j] = run;
    run += v[j];
  }
  if (tid == 255) bsum[blockIdx.x] = sh[255];
}

__global__ void k_scan2(const int* __restrict__ bsum, int* __restrict__ bpre) {
  __shared__ int sh[256];
  const int tid = threadIdx.x;
  const int v = (tid < kScanBlocks) ? bsum[tid] : 0;
  sh[tid] = v;
  __syncthreads();
  for (int o = 1; o < 256; o <<= 1) {
    int t = (tid >= o) ? sh[tid - o] : 0;
    __syncthreads();
    sh[tid] += t;
    __syncthreads();
  }
  if (tid < kScanBlocks) bpre[tid] = sh[tid] - v;
}

__global__ void k_scan3(int* __restrict__ off, int* __restrict__ cursor,
                        const int* __restrict__ bpre) {
  const int i = blockIdx.x * 256 + threadIdx.x;
  if (i < kSEG) {
    const int val = off[i] + bpre[i >> 10];
    off[i] = val;
    cursor[i] = val;
  }
  if (i == 0) off[kSEG] = kETOT;
}

__global__ void k_fill(const int* __restrict__ ei, int E, int segbase,
                       int srcoff, int* __restrict__ cursor,
                       int* __restrict__ elist) {
  const int i = blockIdx.x * 256 + threadIdx.x;
  if (i < E) {
    const int d = ei[E + i];
    const int pos = atomicAdd(&cursor[segbase + d], 1);
    elist[pos] = ei[i] + srcoff;
  }
}

__global__ void k_invdeg(const int* __restrict__ cnt,
                         float* __restrict__ invdeg) {
  const int i = blockIdx.x * 256 + threadIdx.x;
  if (i < kSEG) {
    const int c = cnt[i];
    invdeg[i] = 1.0f / (float)(c > 0 ? c : 1);
  }
}

// ---------------------------------------------------------------------------
// Stacked B build: BF = [W_r1; W_r2; root], BA = [W_r0; W_r3; root]  (fp32)
// W_r = sum_b comp[r,b] * basis[b]
// ---------------------------------------------------------------------------
__global__ void k_build_B(const float* __restrict__ comp_l,
                          const float* __restrict__ basis_l,
                          const float* __restrict__ root_l,
                          float* __restrict__ BF, float* __restrict__ BA) {
  const int idx = blockIdx.x * 256 + threadIdx.x;
  if (idx >= 2 * kK * kH) return;
  const int t = idx / (kK * kH);
  const int rem = idx % (kK * kH);
  const int row = rem >> 8;   // 0..767
  const int col = rem & 255;
  const int slot = row >> 8;  // 0,1,2
  const int wrow = row & 255;
  float val;
  if (slot == 2) {
    val = root_l[wrow * kH + col];
  } else {
    const int r = (t == 0) ? (slot == 0 ? 1 : 2) : (slot == 0 ? 0 : 3);
    const int io = wrow * kH + col;
    val = comp_l[r * kB + 0] * basis_l[0 * kH * kH + io] +
          comp_l[r * kB + 1] * basis_l[1 * kH * kH + io] +
          comp_l[r * kB + 2] * basis_l[2 * kH * kH + io];
  }
  (t == 0 ? BF : BA)[row * kH + col] = val;
}

// ---------------------------------------------------------------------------
// Gather-mean into A-chunk slot: A[d, slot*256..] = mean of x[src] (bf16)
// One wave per destination.
// ---------------------------------------------------------------------------
__global__ __launch_bounds__(256) void k_gather(
    const unsigned short* __restrict__ x, unsigned short* __restrict__ A,
    const int* __restrict__ off, const int* __restrict__ elist,
    const float* __restrict__ invdeg, int segbase, int c0, int nrows,
    int slot) {
  const int wave = threadIdx.x >> 6;
  const int lane = threadIdx.x & 63;
  const int d = blockIdx.x * 4 + wave;
  if (d >= nrows) return;
  const int s = segbase + c0 + d;
  const int lo = off[s], hi = off[s + 1];
  const float iv = invdeg[s];
  float4 sum = make_float4(0.f, 0.f, 0.f, 0.f);
  for (int e = lo; e < hi; ++e) {
    const int src = elist[e];
    const ushort4 v = *(const ushort4*)&x[(size_t)src * kH + (lane << 2)];
    sum.x += b2f(v.x);
    sum.y += b2f(v.y);
    sum.z += b2f(v.z);
    sum.w += b2f(v.w);
  }
  ushort4 o;
  o.x = f2b(sum.x * iv);
  o.y = f2b(sum.y * iv);
  o.z = f2b(sum.z * iv);
  o.w = f2b(sum.w * iv);
  *(ushort4*)&A[(size_t)d * kK + slot * kH + (lane << 2)] = o;
}

// Copy x rows into A-chunk slot 2 (cols 512..767). 16B per thread.
__global__ void k_copyx(const unsigned short* __restrict__ x,
                        unsigned short* __restrict__ A, int xrow0, int nrows) {
  const int idx = blockIdx.x * 256 + threadIdx.x;  // nrows * 32
  const int r = idx >> 5;
  const int c8 = idx & 31;
  if (r < nrows) {
    *(uint4*)&A[(size_t)r * kK + 512 + c8 * 8] =
        *(const uint4*)&x[(size_t)(xrow0 + r) * kH + c8 * 8];
  }
}

// ---------------------------------------------------------------------------
// GEMM: C[M][256] = A[M][768](bf16) @ B[768][256](fp32) + bias, bf16 out.
// 64x64 tile, BK=16, 256 threads, 4x4 micro-tile.
// ---------------------------------------------------------------------------
__global__ __launch_bounds__(256) void k_gemm_cat(
    const unsigned short* __restrict__ A, const float* __restrict__ B,
    unsigned short* __restrict__ C, const float* __restrict__ bias, int M) {
  __shared__ float As[16][68];
  __shared__ float Bs[16][68];
  const int tid = threadIdx.x;
  const int tx = tid & 15, ty = tid >> 4;
  const int brow = blockIdx.x * 64;
  const int bcol = blockIdx.y * 64;

  const int lr = tid >> 2;          // 0..63  A load row
  const int lk = (tid & 3) << 2;    // 0,4,8,12
  const int bkr = tid >> 4;         // 0..15 B load row
  const int bnc = (tid & 15) << 2;  // 0..60
  const bool arow_ok = (brow + lr) < M;

  float acc[4][4];
#pragma unroll
  for (int i = 0; i < 4; ++i)
#pragma unroll
    for (int j = 0; j < 4; ++j) acc[i][j] = 0.f;

  for (int kt = 0; kt < kK; kt += 16) {
    float4 av = make_float4(0.f, 0.f, 0.f, 0.f);
    if (arow_ok) {
      const ushort4 a = *(const ushort4*)&A[(size_t)(brow + lr) * kK + kt + lk];
      av.x = b2f(a.x);
      av.y = b2f(a.y);
      av.z = b2f(a.z);
      av.w = b2f(a.w);
    }
    const float4 bv = *(const float4*)&B[(size_t)(kt + bkr) * kH + bcol + bnc];
    __syncthreads();
    As[lk + 0][lr] = av.x;
    As[lk + 1][lr] = av.y;
    As[lk + 2][lr] = av.z;
    As[lk + 3][lr] = av.w;
    *(float4*)&Bs[bkr][bnc] = bv;
    __syncthreads();
#pragma unroll
    for (int k = 0; k < 16; ++k) {
      const float4 a4 = *(const float4*)&As[k][ty << 2];
      const float4 b4 = *(const float4*)&Bs[k][tx << 2];
      acc[0][0] += a4.x * b4.x; acc[0][1] += a4.x * b4.y;
      acc[0][2] += a4.x * b4.z; acc[0][3] += a4.x * b4.w;
      acc[1][0] += a4.y * b4.x; acc[1][1] += a4.y * b4.y;
      acc[1][2] += a4.y * b4.z; acc[1][3] += a4.y * b4.w;
      acc[2][0] += a4.z * b4.x; acc[2][1] += a4.z * b4.y;
      acc[2][2] += a4.z * b4.z; acc[2][3] += a4.z * b4.w;
      acc[3][0] += a4.w * b4.x; acc[3][1] += a4.w * b4.y;
      acc[3][2] += a4.w * b4.z; acc[3][3] += a4.w * b4.w;
    }
  }

  const int orow = brow + (ty << 2);
  const int ocol = bcol + (tx << 2);
  const float4 bb = *(const float4*)&bias[ocol];
#pragma unroll
  for (int i = 0; i < 4; ++i) {
    const int r = orow + i;
    if (r < M) {
      ushort4 o;
      o.x = f2b(acc[i][0] + bb.x);
      o.y = f2b(acc[i][1] + bb.y);
      o.z = f2b(acc[i][2] + bb.z);
      o.w = f2b(acc[i][3] + bb.w);
      *(ushort4*)&C[(size_t)r * kH + ocol] = o;
    }
  }
}

// ---------------------------------------------------------------------------
// x = leaky(LN(h)) + x   (bf16 io, fp32 math). One wave per row.
// ---------------------------------------------------------------------------
__global__ __launch_bounds__(256) void k_ln_res(
    const unsigned short* __restrict__ h, unsigned short* __restrict__ x,
    const float* __restrict__ gamma, const float* __restrict__ beta) {
  const int wave = threadIdx.x >> 6;
  const int lane = threadIdx.x & 63;
  const int row = blockIdx.x * 4 + wave;
  if (row >= kN) return;
  const ushort4 hv = *(const ushort4*)&h[(size_t)row * kH + (lane << 2)];
  float v0 = b2f(hv.x), v1 = b2f(hv.y), v2 = b2f(hv.z), v3 = b2f(hv.w);
  float s = v0 + v1 + v2 + v3;
  float ss = v0 * v0 + v1 * v1 + v2 * v2 + v3 * v3;
#pragma unroll
  for (int o = 1; o < 64; o <<= 1) {
    s += __shfl_xor(s, o);
    ss += __shfl_xor(ss, o);
  }
  const float mu = s * (1.f / kH);
  const float var = ss * (1.f / kH) - mu * mu;
  const float rs = rsqrtf(var + 1e-5f);
  const float4 g = *(const float4*)&gamma[lane << 2];
  const float4 b = *(const float4*)&beta[lane << 2];
  float t0 = (v0 - mu) * rs * g.x + b.x;
  float t1 = (v1 - mu) * rs * g.y + b.y;
  float t2 = (v2 - mu) * rs * g.z + b.z;
  float t3 = (v3 - mu) * rs * g.w + b.w;
  t0 = t0 > 0.f ? t0 : 0.1f * t0;
  t1 = t1 > 0.f ? t1 : 0.1f * t1;
  t2 = t2 > 0.f ? t2 : 0.1f * t2;
  t3 = t3 > 0.f ? t3 : 0.1f * t3;
  const ushort4 xv = *(const ushort4*)&x[(size_t)row * kH + (lane << 2)];
  ushort4 o;
  o.x = f2b(b2f(xv.x) + t0);
  o.y = f2b(b2f(xv.y) + t1);
  o.z = f2b(b2f(xv.z) + t2);
  o.w = f2b(b2f(xv.w) + t3);
  *(ushort4*)&x[(size_t)row * kH + (lane << 2)] = o;
}

// ---------------------------------------------------------------------------
// Readout: out[n] = dot(x[n], ro_w) + ro_b  (flight rows), fp32 out.
// ---------------------------------------------------------------------------
__global__ __launch_bounds__(256) void k_readout(
    const unsigned short* __restrict__ x, const float* __restrict__ w,
    const float* __restrict__ b, float* __restrict__ out) {
  const int wave = threadIdx.x >> 6;
  const int lane = threadIdx.x & 63;
  const int row = blockIdx.x * 4 + wave;
  if (row >= kNF) return;
  const ushort4 v = *(const ushort4*)&x[(size_t)row * kH + (lane << 2)];
  const float4 wv = *(const float4*)&w[lane << 2];
  float s = b2f(v.x) * wv.x + b2f(v.y) * wv.y + b2f(v.z) * wv.z +
            b2f(v.w) * wv.w;
#pragma unroll
  for (int o = 1; o < 64; o <<= 1) s += __shfl_xor(s, o);
  if (lane == 0) out[row] = s + b[0];
}

}  // namespace

// ---------------------------------------------------------------------------
extern "C" void kernel_launch(void* const* d_in, const int* in_sizes, int n_in,
                              void* d_out, int out_size, void* d_ws,
                              size_t ws_size, hipStream_t stream) {
  const float* x_flight = (const float*)d_in[0];
  const float* x_airport = (const float*)d_in[1];
  const float* enc_w_f = (const float*)d_in[2];
  const float* enc_b_f = (const float*)d_in[3];
  const float* enc_w_a = (const float*)d_in[4];
  const float* enc_b_a = (const float*)d_in[5];
  const float* basis = (const float*)d_in[6];
  const float* comp = (const float*)d_in[7];
  const float* root = (const float*)d_in[8];
  const float* conv_bias = (const float*)d_in[9];
  const float* ln_gamma = (const float*)d_in[10];
  const float* ln_beta = (const float*)d_in[11];
  const float* ro_w = (const float*)d_in[12];
  const float* ro_b = (const float*)d_in[13];
  const int* ei_fa = (const int*)d_in[14];
  const int* ei_af = (const int*)d_in[15];
  const int* ei_ff = (const int*)d_in[16];
  const int* ei_aa = (const int*)d_in[17];
  float* out = (float*)d_out;

  // workspace carve (fixed buffers first, then adaptive A-chunk)
  char* base = (char*)d_ws;
  size_t off_b = 0;
  auto carve = [&](size_t bytes) -> char* {
    char* p = base + off_b;
    off_b += (bytes + 255) & ~(size_t)255;
    return p;
  };
  unsigned short* xbuf = (unsigned short*)carve((size_t)kN * kH * 2);
  unsigned short* hbuf = (unsigned short*)carve((size_t)kN * kH * 2);
  float* BF = (float*)carve((size_t)kK * kH * 4);
  float* BA = (float*)carve((size_t)kK * kH * 4);
  int* cnt = (int*)carve((size_t)kSEG * 4);
  int* offs = (int*)carve((size_t)(kSEG + 1) * 4);
  int* cursor = (int*)carve((size_t)kSEG * 4);
  int* elist = (int*)carve((size_t)kETOT * 4);
  int* bsum = (int*)carve((size_t)kScanBlocks * 4);
  int* bpre = (int*)carve((size_t)kScanBlocks * 4);
  float* invdeg = (float*)carve((size_t)kSEG * 4);
  // adaptive chunk rows (multiple of 64, cap 16384)
  size_t rem = (ws_size > off_b + 4096) ? (ws_size - off_b - 4096) : 0;
  int CH = (int)(rem / ((size_t)kK * 2));
  if (CH > 16384) CH = 16384;
  CH &= ~63;
  if (CH < 64) CH = 64;  // (ws_size too small to function; best effort)
  unsigned short* Achunk = (unsigned short*)carve((size_t)CH * kK * 2);

  // --- encoders ---
  k_encoder<32><<<kNF / 32, 256, 0, stream>>>(x_flight, enc_w_f, enc_b_f, xbuf,
                                              kNF, 0);
  k_encoder<16><<<kNA / 32, 256, 0, stream>>>(x_airport, enc_w_a, enc_b_a, xbuf,
                                              kNA, kNF);

  // --- CSR build ---
  hipMemsetAsync(cnt, 0, (size_t)kSEG * 4, stream);
  const int b0 = 0, b1 = kNA, b2 = kNA + kNF, b3 = kNA + 2 * kNF;
  k_count<<<(kEFA + 255) / 256, 256, 0, stream>>>(ei_fa, kEFA, b0, cnt);
  k_count<<<(kEAF + 255) / 256, 256, 0, stream>>>(ei_af, kEAF, b1, cnt);
  k_count<<<(kEFF + 255) / 256, 256, 0, stream>>>(ei_ff, kEFF, b2, cnt);
  k_count<<<(kEAA + 255) / 256, 256, 0, stream>>>(ei_aa, kEAA, b3, cnt);
  k_scan1<<<kScanBlocks, 256, 0, stream>>>(cnt, offs, bsum);
  k_scan2<<<1, 256, 0, stream>>>(bsum, bpre);
  k_scan3<<<(kSEG + 255) / 256, 256, 0, stream>>>(offs, cursor, bpre);
  k_invdeg<<<(kSEG + 255) / 256, 256, 0, stream>>>(cnt, invdeg);
  k_fill<<<(kEFA + 255) / 256, 256, 0, stream>>>(ei_fa, kEFA, b0, 0, cursor,
                                                 elist);
  k_fill<<<(kEAF + 255) / 256, 256, 0, stream>>>(ei_af, kEAF, b1, kNF, cursor,
                                                 elist);
  k_fill<<<(kEFF + 255) / 256, 256, 0, stream>>>(ei_ff, kEFF, b2, 0, cursor,
                                                 elist);
  k_fill<<<(kEAA + 255) / 256, 256, 0, stream>>>(ei_aa, kEAA, b3, kNF, cursor,
                                                 elist);

  // --- layers ---
  for (int l = 0; l < kL; ++l) {
    const float* comp_l = comp + (size_t)l * 4 * kB;
    const float* basis_l = basis + (size_t)l * kB * kH * kH;
    const float* root_l = root + (size_t)l * kH * kH;
    const float* bias_l = conv_bias + (size_t)l * kH;
    const float* gamma_l = ln_gamma + (size_t)l * kH;
    const float* beta_l = ln_beta + (size_t)l * kH;

    k_build_B<<<(2 * kK * kH + 255) / 256, 256, 0, stream>>>(comp_l, basis_l,
                                                             root_l, BF, BA);

    // flight rows: slots {r1(af), r2(ff), x}, h rows [0, kNF)
    for (int c0 = 0; c0 < kNF; c0 += CH) {
      const int rows = (kNF - c0 < CH) ? (kNF - c0) : CH;
      k_copyx<<<(rows * 32 + 255) / 256, 256, 0, stream>>>(xbuf, Achunk, c0,
                                                           rows);
      k_gather<<<(rows + 3) / 4, 256, 0, stream>>>(xbuf, Achunk, offs, elist,
                                                   invdeg, b1, c0, rows, 0);
      k_gather<<<(rows + 3) / 4, 256, 0, stream>>>(xbuf, Achunk, offs, elist,
                                                   invdeg, b2, c0, rows, 1);
      dim3 g((rows + 63) / 64, 4);
      k_gemm_cat<<<g, 256, 0, stream>>>(Achunk, BF, hbuf + (size_t)c0 * kH,
                                        bias_l, rows);
    }
    // airport rows: slots {r0(fa), r3(aa), x}, h rows [kNF, kN)
    for (int c0 = 0; c0 < kNA; c0 += CH) {
      const int rows = (kNA - c0 < CH) ? (kNA - c0) : CH;
      k_copyx<<<(rows * 32 + 255) / 256, 256, 0, stream>>>(xbuf, Achunk,
                                                           kNF + c0, rows);
      k_gather<<<(rows + 3) / 4, 256, 0, stream>>>(xbuf, Achunk, offs, elist,
                                                   invdeg, b0, c0, rows, 0);
      k_gather<<<(rows + 3) / 4, 256, 0, stream>>>(xbuf, Achunk, offs, elist,
                                                   invdeg, b3, c0, rows, 1);
      dim3 g((rows + 63) / 64, 4);
      k_gemm_cat<<<g, 256, 0, stream>>>(
          Achunk, BA, hbuf + (size_t)(kNF + c0) * kH, bias_l, rows);
    }

    k_ln_res<<<(kN + 3) / 4, 256, 0, stream>>>(hbuf, xbuf, gamma_l, beta_l);
  }

  // --- readout ---
  k_readout<<<(kNF + 3) / 4, 256, 0, stream>>>(xbuf, ro_w, ro_b, out);
}

// Round 3
// 2016.886 us; speedup vs baseline: 1.8960x; 1.8960x over previous
//
#include <hip/hip_runtime.h>
#include <cstdint>

// ---------------------------------------------------------------------------
// RGCN (flight/airport heterograph).
// bf16 activation storage; GEMM on MFMA (bf16 in, fp32 accum).
// Per layer, per node type:
//   A = [agg_relA | agg_relB | x]  (K=768, bf16, chunked)
//   h = A @ [W_a; W_b; root] + bias   (MFMA GEMM, B prebuilt bf16 transposed)
//   x = leaky(LN(h)) + x
// CSR built on-device once per call (count -> scan -> fill).
// ---------------------------------------------------------------------------

namespace {

constexpr int kNF = 100000;
constexpr int kNA = 4000;
constexpr int kN  = 104000;
constexpr int kH  = 256;
constexpr int kL  = 4;
constexpr int kB  = 3;
constexpr int kEFA = 200000;
constexpr int kEAF = 200000;
constexpr int kEFF = 400000;
constexpr int kEAA = 40000;
constexpr int kETOT = 840000;
constexpr int kK = 768;  // concat K: 2 agg slots + x
// segment space (concatenated per-relation dst ranges):
// r0 fa->airport [0,kNA) | r1 af->flight [kNA,kNA+kNF)
// r2 ff->flight [kNA+kNF, kNA+2kNF) | r3 aa->airport [kNA+2kNF, kSEG)
constexpr int kSEG = 2 * kNA + 2 * kNF;           // 208000
constexpr int kScanBlocks = (kSEG + 1023) / 1024; // 204

typedef __attribute__((ext_vector_type(8))) short short8v;
typedef __attribute__((ext_vector_type(4))) float float4v;

__device__ __forceinline__ float b2f(unsigned short u) {
  union { unsigned int i; float f; } v;
  v.i = ((unsigned int)u) << 16;
  return v.f;
}
__device__ __forceinline__ unsigned short f2b(float f) {
  union { float f; unsigned int i; } v;
  v.f = f;
  unsigned int x = v.i;
  x += 0x7fffu + ((x >> 16) & 1u);  // round-to-nearest-even
  return (unsigned short)(x >> 16);
}

// ---------------------------------------------------------------------------
// Encoders: xout[rowoff+i] = xin[i] @ W + bias   (W [KIN][256]), bf16 out
// ---------------------------------------------------------------------------
template <int KIN>
__global__ __launch_bounds__(256) void k_encoder(
    const float* __restrict__ xin, const float* __restrict__ W,
    const float* __restrict__ bias, unsigned short* __restrict__ xout, int M,
    int rowoff) {
  __shared__ float xs[32][KIN];
  const int tid = threadIdx.x;
  const int r0 = blockIdx.x * 32;
  constexpr int TOT = 32 * KIN;
  for (int idx = tid * 4; idx < TOT; idx += 256 * 4) {
    const int rr = idx / KIN;
    const int kk = idx % KIN;
    *(float4*)&xs[rr][kk] = *(const float4*)&xin[(size_t)(r0 + rr) * KIN + kk];
  }
  __syncthreads();
  float acc[32];
#pragma unroll
  for (int i = 0; i < 32; ++i) acc[i] = 0.f;
  for (int k = 0; k < KIN; ++k) {
    const float wk = W[k * kH + tid];
#pragma unroll
    for (int i = 0; i < 32; ++i) acc[i] += xs[i][k] * wk;
  }
  const float bb = bias[tid];
#pragma unroll
  for (int i = 0; i < 32; ++i) {
    const int r = r0 + i;
    if (r < M) xout[(size_t)(rowoff + r) * kH + tid] = f2b(acc[i] + bb);
  }
}

// ---------------------------------------------------------------------------
// CSR build
// ---------------------------------------------------------------------------
__global__ void k_count(const int* __restrict__ ei, int E, int segbase,
                        int* __restrict__ cnt) {
  const int i = blockIdx.x * 256 + threadIdx.x;
  if (i < E) atomicAdd(&cnt[segbase + ei[E + i]], 1);
}

__global__ void k_scan1(const int* __restrict__ cnt, int* __restrict__ out,
                        int* __restrict__ bsum) {
  __shared__ int sh[256];
  const int tid = threadIdx.x;
  const int base = blockIdx.x * 1024 + tid * 4;
  int v[4];
#pragma unroll
  for (int j = 0; j < 4; ++j) v[j] = (base + j < kSEG) ? cnt[base + j] : 0;
  const int tsum = v[0] + v[1] + v[2] + v[3];
  sh[tid] = tsum;
  __syncthreads();
  for (int o = 1; o < 256; o <<= 1) {
    int t = (tid >= o) ? sh[tid - o] : 0;
    __syncthreads();
    sh[tid] += t;
    __syncthreads();
  }
  const int excl = sh[tid] - tsum;
  int run = excl;
#pragma unroll
  for (int j = 0; j < 4; ++j) {
    if (base + j < kSEG) out[base + j] = run;
    run += v[j];
  }
  if (tid == 255) bsum[blockIdx.x] = sh[255];
}

__global__ void k_scan2(const int* __restrict__ bsum, int* __restrict__ bpre) {
  __shared__ int sh[256];
  const int tid = threadIdx.x;
  const int v = (tid < kScanBlocks) ? bsum[tid] : 0;
  sh[tid] = v;
  __syncthreads();
  for (int o = 1; o < 256; o <<= 1) {
    int t = (tid >= o) ? sh[tid - o] : 0;
    __syncthreads();
    sh[tid] += t;
    __syncthreads();
  }
  if (tid < kScanBlocks) bpre[tid] = sh[tid] - v;
}

__global__ void k_scan3(int* __restrict__ off, int* __restrict__ cursor,
                        const int* __restrict__ bpre) {
  const int i = blockIdx.x * 256 + threadIdx.x;
  if (i < kSEG) {
    const int val = off[i] + bpre[i >> 10];
    off[i] = val;
    cursor[i] = val;
  }
  if (i == 0) off[kSEG] = kETOT;
}

__global__ void k_fill(const int* __restrict__ ei, int E, int segbase,
                       int srcoff, int* __restrict__ cursor,
                       int* __restrict__ elist) {
  const int i = blockIdx.x * 256 + threadIdx.x;
  if (i < E) {
    const int d = ei[E + i];
    const int pos = atomicAdd(&cursor[segbase + d], 1);
    elist[pos] = ei[i] + srcoff;
  }
}

__global__ void k_invdeg(const int* __restrict__ cnt,
                         float* __restrict__ invdeg) {
  const int i = blockIdx.x * 256 + threadIdx.x;
  if (i < kSEG) {
    const int c = cnt[i];
    invdeg[i] = 1.0f / (float)(c > 0 ? c : 1);
  }
}

// ---------------------------------------------------------------------------
// Stacked transposed B build (bf16):
//   BtF[n][k] = ([W_r1; W_r2; root])[k][n],  BtA likewise with {r0, r3}.
//   W_r = sum_b comp[r,b] * basis[b]
// ---------------------------------------------------------------------------
__global__ void k_build_Bt(const float* __restrict__ comp_l,
                           const float* __restrict__ basis_l,
                           const float* __restrict__ root_l,
                           unsigned short* __restrict__ BtF,
                           unsigned short* __restrict__ BtA) {
  const int idx = blockIdx.x * 256 + threadIdx.x;
  if (idx >= 2 * kK * kH) return;
  const int t = idx / (kK * kH);
  const int rem = idx % (kK * kH);
  const int n = rem / kK;     // 0..255 output col
  const int k = rem % kK;     // 0..767
  const int slot = k >> 8;    // 0,1,2
  const int wrow = k & 255;
  float val;
  if (slot == 2) {
    val = root_l[wrow * kH + n];
  } else {
    const int r = (t == 0) ? (slot == 0 ? 1 : 2) : (slot == 0 ? 0 : 3);
    const int io = wrow * kH + n;
    val = comp_l[r * kB + 0] * basis_l[0 * kH * kH + io] +
          comp_l[r * kB + 1] * basis_l[1 * kH * kH + io] +
          comp_l[r * kB + 2] * basis_l[2 * kH * kH + io];
  }
  (t == 0 ? BtF : BtA)[(size_t)n * kK + k] = f2b(val);
}

// ---------------------------------------------------------------------------
// Gather-mean into A-chunk slot: A[d, slot*256..] = mean of x[src] (bf16)
// One wave per destination.
// ---------------------------------------------------------------------------
__global__ __launch_bounds__(256) void k_gather(
    const unsigned short* __restrict__ x, unsigned short* __restrict__ A,
    const int* __restrict__ off, const int* __restrict__ elist,
    const float* __restrict__ invdeg, int segbase, int c0, int nrows,
    int slot) {
  const int wave = threadIdx.x >> 6;
  const int lane = threadIdx.x & 63;
  const int d = blockIdx.x * 4 + wave;
  if (d >= nrows) return;
  const int s = segbase + c0 + d;
  const int lo = off[s], hi = off[s + 1];
  const float iv = invdeg[s];
  float4 sum = make_float4(0.f, 0.f, 0.f, 0.f);
  for (int e = lo; e < hi; ++e) {
    const int src = elist[e];
    const ushort4 v = *(const ushort4*)&x[(size_t)src * kH + (lane << 2)];
    sum.x += b2f(v.x);
    sum.y += b2f(v.y);
    sum.z += b2f(v.z);
    sum.w += b2f(v.w);
  }
  ushort4 o;
  o.x = f2b(sum.x * iv);
  o.y = f2b(sum.y * iv);
  o.z = f2b(sum.z * iv);
  o.w = f2b(sum.w * iv);
  *(ushort4*)&A[(size_t)d * kK + slot * kH + (lane << 2)] = o;
}

// Copy x rows into A-chunk slot 2 (cols 512..767). 16B per thread.
__global__ void k_copyx(const unsigned short* __restrict__ x,
                        unsigned short* __restrict__ A, int xrow0, int nrows) {
  const int idx = blockIdx.x * 256 + threadIdx.x;  // nrows * 32
  const int r = idx >> 5;
  const int c8 = idx & 31;
  if (r < nrows) {
    *(uint4*)&A[(size_t)r * kK + 512 + c8 * 8] =
        *(const uint4*)&x[(size_t)(xrow0 + r) * kH + c8 * 8];
  }
}

// ---------------------------------------------------------------------------
// MFMA GEMM: C[M][256] = A[M][768](bf16) @ Bt^T + bias, bf16 out.
// Bt is [256][768] bf16 (row n = column n of B, contiguous in K).
// Block: 256 threads (4 waves), tile 64 rows x 128 cols (grid.y = 2 halves).
// Wave w covers cols blockIdx.y*128 + w*32 (4 m-frags x 2 n-frags of 16x16).
// A tile staged in LDS, stride 40 bf16 (80 B) -> conflict-free-ish reads.
// ---------------------------------------------------------------------------
__global__ __launch_bounds__(256) void k_gemm_mfma(
    const unsigned short* __restrict__ A, const unsigned short* __restrict__ Bt,
    unsigned short* __restrict__ C, const float* __restrict__ bias, int M) {
  __shared__ unsigned short As[64][40];
  const int tid = threadIdx.x;
  const int wave = tid >> 6;
  const int lane = tid & 63;
  const int brow = blockIdx.x * 64;
  const int ncol0 = blockIdx.y * 128 + wave * 32;

  const int lrow = tid >> 2;        // 0..63 staging row
  const int lk8 = (tid & 3) * 8;    // 0,8,16,24 (bf16 units, 16B granules)

  const int fr = lane & 15;         // fragment row/col within 16
  const int fq = lane >> 4;         // 0..3 k-octet / acc row group

  const bool arow_ok = (brow + lrow) < M;
  const unsigned short* Arow = A + (size_t)(brow + lrow) * kK + lk8;
  const unsigned short* Bt0 = Bt + (size_t)(ncol0 + fr) * kK + fq * 8;

  float4v acc[4][2];
#pragma unroll
  for (int mi = 0; mi < 4; ++mi)
#pragma unroll
    for (int ni = 0; ni < 2; ++ni) acc[mi][ni] = (float4v)(0.f);

  for (int kt = 0; kt < kK; kt += 32) {
    uint4 av = make_uint4(0, 0, 0, 0);
    if (arow_ok) av = *(const uint4*)(Arow + kt);
    short8v bfrag[2];
#pragma unroll
    for (int ni = 0; ni < 2; ++ni)
      bfrag[ni] = *(const short8v*)(Bt0 + (size_t)ni * 16 * kK + kt);
    __syncthreads();  // previous iter's LDS reads done
    *(uint4*)&As[lrow][lk8] = av;
    __syncthreads();
    short8v afrag[4];
#pragma unroll
    for (int mi = 0; mi < 4; ++mi)
      afrag[mi] = *(const short8v*)&As[mi * 16 + fr][fq * 8];
#pragma unroll
    for (int mi = 0; mi < 4; ++mi)
#pragma unroll
      for (int ni = 0; ni < 2; ++ni)
        acc[mi][ni] = __builtin_amdgcn_mfma_f32_16x16x32_bf16(
            afrag[mi], bfrag[ni], acc[mi][ni], 0, 0, 0);
  }

  // epilogue: C row = brow + mi*16 + fq*4 + reg, col = ncol0 + ni*16 + fr
#pragma unroll
  for (int ni = 0; ni < 2; ++ni) {
    const int col = ncol0 + ni * 16 + fr;
    const float bb = bias[col];
#pragma unroll
    for (int mi = 0; mi < 4; ++mi) {
      const int row0 = brow + mi * 16 + fq * 4;
#pragma unroll
      for (int reg = 0; reg < 4; ++reg) {
        const int r = row0 + reg;
        if (r < M) C[(size_t)r * kH + col] = f2b(acc[mi][ni][reg] + bb);
      }
    }
  }
}

// ---------------------------------------------------------------------------
// x = leaky(LN(h)) + x   (bf16 io, fp32 math). One wave per row.
// ---------------------------------------------------------------------------
__global__ __launch_bounds__(256) void k_ln_res(
    const unsigned short* __restrict__ h, unsigned short* __restrict__ x,
    const float* __restrict__ gamma, const float* __restrict__ beta) {
  const int wave = threadIdx.x >> 6;
  const int lane = threadIdx.x & 63;
  const int row = blockIdx.x * 4 + wave;
  if (row >= kN) return;
  const ushort4 hv = *(const ushort4*)&h[(size_t)row * kH + (lane << 2)];
  float v0 = b2f(hv.x), v1 = b2f(hv.y), v2 = b2f(hv.z), v3 = b2f(hv.w);
  float s = v0 + v1 + v2 + v3;
  float ss = v0 * v0 + v1 * v1 + v2 * v2 + v3 * v3;
#pragma unroll
  for (int o = 1; o < 64; o <<= 1) {
    s += __shfl_xor(s, o);
    ss += __shfl_xor(ss, o);
  }
  const float mu = s * (1.f / kH);
  const float var = ss * (1.f / kH) - mu * mu;
  const float rs = rsqrtf(var + 1e-5f);
  const float4 g = *(const float4*)&gamma[lane << 2];
  const float4 b = *(const float4*)&beta[lane << 2];
  float t0 = (v0 - mu) * rs * g.x + b.x;
  float t1 = (v1 - mu) * rs * g.y + b.y;
  float t2 = (v2 - mu) * rs * g.z + b.z;
  float t3 = (v3 - mu) * rs * g.w + b.w;
  t0 = t0 > 0.f ? t0 : 0.1f * t0;
  t1 = t1 > 0.f ? t1 : 0.1f * t1;
  t2 = t2 > 0.f ? t2 : 0.1f * t2;
  t3 = t3 > 0.f ? t3 : 0.1f * t3;
  const ushort4 xv = *(const ushort4*)&x[(size_t)row * kH + (lane << 2)];
  ushort4 o;
  o.x = f2b(b2f(xv.x) + t0);
  o.y = f2b(b2f(xv.y) + t1);
  o.z = f2b(b2f(xv.z) + t2);
  o.w = f2b(b2f(xv.w) + t3);
  *(ushort4*)&x[(size_t)row * kH + (lane << 2)] = o;
}

// ---------------------------------------------------------------------------
// Readout: out[n] = dot(x[n], ro_w) + ro_b  (flight rows), fp32 out.
// ---------------------------------------------------------------------------
__global__ __launch_bounds__(256) void k_readout(
    const unsigned short* __restrict__ x, const float* __restrict__ w,
    const float* __restrict__ b, float* __restrict__ out) {
  const int wave = threadIdx.x >> 6;
  const int lane = threadIdx.x & 63;
  const int row = blockIdx.x * 4 + wave;
  if (row >= kNF) return;
  const ushort4 v = *(const ushort4*)&x[(size_t)row * kH + (lane << 2)];
  const float4 wv = *(const float4*)&w[lane << 2];
  float s = b2f(v.x) * wv.x + b2f(v.y) * wv.y + b2f(v.z) * wv.z +
            b2f(v.w) * wv.w;
#pragma unroll
  for (int o = 1; o < 64; o <<= 1) s += __shfl_xor(s, o);
  if (lane == 0) out[row] = s + b[0];
}

}  // namespace

// ---------------------------------------------------------------------------
extern "C" void kernel_launch(void* const* d_in, const int* in_sizes, int n_in,
                              void* d_out, int out_size, void* d_ws,
                              size_t ws_size, hipStream_t stream) {
  const float* x_flight = (const float*)d_in[0];
  const float* x_airport = (const float*)d_in[1];
  const float* enc_w_f = (const float*)d_in[2];
  const float* enc_b_f = (const float*)d_in[3];
  const float* enc_w_a = (const float*)d_in[4];
  const float* enc_b_a = (const float*)d_in[5];
  const float* basis = (const float*)d_in[6];
  const float* comp = (const float*)d_in[7];
  const float* root = (const float*)d_in[8];
  const float* conv_bias = (const float*)d_in[9];
  const float* ln_gamma = (const float*)d_in[10];
  const float* ln_beta = (const float*)d_in[11];
  const float* ro_w = (const float*)d_in[12];
  const float* ro_b = (const float*)d_in[13];
  const int* ei_fa = (const int*)d_in[14];
  const int* ei_af = (const int*)d_in[15];
  const int* ei_ff = (const int*)d_in[16];
  const int* ei_aa = (const int*)d_in[17];
  float* out = (float*)d_out;

  // workspace carve (fixed buffers first, then adaptive A-chunk)
  char* base = (char*)d_ws;
  size_t off_b = 0;
  auto carve = [&](size_t bytes) -> char* {
    char* p = base + off_b;
    off_b += (bytes + 255) & ~(size_t)255;
    return p;
  };
  unsigned short* xbuf = (unsigned short*)carve((size_t)kN * kH * 2);
  unsigned short* hbuf = (unsigned short*)carve((size_t)kN * kH * 2);
  unsigned short* BtF = (unsigned short*)carve((size_t)kK * kH * 2);
  unsigned short* BtA = (unsigned short*)carve((size_t)kK * kH * 2);
  int* cnt = (int*)carve((size_t)kSEG * 4);
  int* offs = (int*)carve((size_t)(kSEG + 1) * 4);
  int* cursor = (int*)carve((size_t)kSEG * 4);
  int* elist = (int*)carve((size_t)kETOT * 4);
  int* bsum = (int*)carve((size_t)kScanBlocks * 4);
  int* bpre = (int*)carve((size_t)kScanBlocks * 4);
  float* invdeg = (float*)carve((size_t)kSEG * 4);
  // adaptive chunk rows (multiple of 64, cap 16384)
  size_t rem = (ws_size > off_b + 4096) ? (ws_size - off_b - 4096) : 0;
  int CH = (int)(rem / ((size_t)kK * 2));
  if (CH > 16384) CH = 16384;
  CH &= ~63;
  if (CH < 64) CH = 64;  // (ws_size too small to function; best effort)
  unsigned short* Achunk = (unsigned short*)carve((size_t)CH * kK * 2);

  // --- encoders ---
  k_encoder<32><<<kNF / 32, 256, 0, stream>>>(x_flight, enc_w_f, enc_b_f, xbuf,
                                              kNF, 0);
  k_encoder<16><<<kNA / 32, 256, 0, stream>>>(x_airport, enc_w_a, enc_b_a, xbuf,
                                              kNA, kNF);

  // --- CSR build ---
  hipMemsetAsync(cnt, 0, (size_t)kSEG * 4, stream);
  const int b0 = 0, b1 = kNA, b2 = kNA + kNF, b3 = kNA + 2 * kNF;
  k_count<<<(kEFA + 255) / 256, 256, 0, stream>>>(ei_fa, kEFA, b0, cnt);
  k_count<<<(kEAF + 255) / 256, 256, 0, stream>>>(ei_af, kEAF, b1, cnt);
  k_count<<<(kEFF + 255) / 256, 256, 0, stream>>>(ei_ff, kEFF, b2, cnt);
  k_count<<<(kEAA + 255) / 256, 256, 0, stream>>>(ei_aa, kEAA, b3, cnt);
  k_scan1<<<kScanBlocks, 256, 0, stream>>>(cnt, offs, bsum);
  k_scan2<<<1, 256, 0, stream>>>(bsum, bpre);
  k_scan3<<<(kSEG + 255) / 256, 256, 0, stream>>>(offs, cursor, bpre);
  k_invdeg<<<(kSEG + 255) / 256, 256, 0, stream>>>(cnt, invdeg);
  k_fill<<<(kEFA + 255) / 256, 256, 0, stream>>>(ei_fa, kEFA, b0, 0, cursor,
                                                 elist);
  k_fill<<<(kEAF + 255) / 256, 256, 0, stream>>>(ei_af, kEAF, b1, kNF, cursor,
                                                 elist);
  k_fill<<<(kEFF + 255) / 256, 256, 0, stream>>>(ei_ff, kEFF, b2, 0, cursor,
                                                 elist);
  k_fill<<<(kEAA + 255) / 256, 256, 0, stream>>>(ei_aa, kEAA, b3, kNF, cursor,
                                                 elist);

  // --- layers ---
  for (int l = 0; l < kL; ++l) {
    const float* comp_l = comp + (size_t)l * 4 * kB;
    const float* basis_l = basis + (size_t)l * kB * kH * kH;
    const float* root_l = root + (size_t)l * kH * kH;
    const float* bias_l = conv_bias + (size_t)l * kH;
    const float* gamma_l = ln_gamma + (size_t)l * kH;
    const float* beta_l = ln_beta + (size_t)l * kH;

    k_build_Bt<<<(2 * kK * kH + 255) / 256, 256, 0, stream>>>(comp_l, basis_l,
                                                              root_l, BtF, BtA);

    // flight rows: slots {r1(af), r2(ff), x}, h rows [0, kNF)
    for (int c0 = 0; c0 < kNF; c0 += CH) {
      const int rows = (kNF - c0 < CH) ? (kNF - c0) : CH;
      k_copyx<<<(rows * 32 + 255) / 256, 256, 0, stream>>>(xbuf, Achunk, c0,
                                                           rows);
      k_gather<<<(rows + 3) / 4, 256, 0, stream>>>(xbuf, Achunk, offs, elist,
                                                   invdeg, b1, c0, rows, 0);
      k_gather<<<(rows + 3) / 4, 256, 0, stream>>>(xbuf, Achunk, offs, elist,
                                                   invdeg, b2, c0, rows, 1);
      dim3 g((rows + 63) / 64, 2);
      k_gemm_mfma<<<g, 256, 0, stream>>>(Achunk, BtF, hbuf + (size_t)c0 * kH,
                                         bias_l, rows);
    }
    // airport rows: slots {r0(fa), r3(aa), x}, h rows [kNF, kN)
    for (int c0 = 0; c0 < kNA; c0 += CH) {
      const int rows = (kNA - c0 < CH) ? (kNA - c0) : CH;
      k_copyx<<<(rows * 32 + 255) / 256, 256, 0, stream>>>(xbuf, Achunk,
                                                           kNF + c0, rows);
      k_gather<<<(rows + 3) / 4, 256, 0, stream>>>(xbuf, Achunk, offs, elist,
                                                   invdeg, b0, c0, rows, 0);
      k_gather<<<(rows + 3) / 4, 256, 0, stream>>>(xbuf, Achunk, offs, elist,
                                                   invdeg, b3, c0, rows, 1);
      dim3 g((rows + 63) / 64, 2);
      k_gemm_mfma<<<g, 256, 0, stream>>>(
          Achunk, BtA, hbuf + (size_t)(kNF + c0) * kH, bias_l, rows);
    }

    k_ln_res<<<(kN + 3) / 4, 256, 0, stream>>>(hbuf, xbuf, gamma_l, beta_l);
  }

  // --- readout ---
  k_readout<<<(kNF + 3) / 4, 256, 0, stream>>>(xbuf, ro_w, ro_b, out);
}

// Round 4
// 1439.695 us; speedup vs baseline: 2.6561x; 1.4009x over previous
//
#include <hip/hip_runtime.h>
#include <cstdint>

// ---------------------------------------------------------------------------
// RGCN (flight/airport heterograph).
// bf16 activation storage; GEMM on MFMA (bf16 in, fp32 accum).
// Per layer, per node type:
//   Aagg = [agg_relA | agg_relB]  (K=512, bf16, chunked)
//   h = [Aagg | x] @ [W_a; W_b; root] + bias   (MFMA GEMM, x read in-place)
//   x = leaky(LN(h)) + x
// CSR built on-device once per call (count -> scan -> fill).
// ---------------------------------------------------------------------------

namespace {

constexpr int kNF = 100000;
constexpr int kNA = 4000;
constexpr int kN  = 104000;
constexpr int kH  = 256;
constexpr int kL  = 4;
constexpr int kB  = 3;
constexpr int kEFA = 200000;
constexpr int kEAF = 200000;
constexpr int kEFF = 400000;
constexpr int kEAA = 40000;
constexpr int kETOT = 840000;
constexpr int kK = 768;   // logical concat K: 2 agg slots + x
constexpr int kKA = 512;  // Aagg row width
// segment space (concatenated per-relation dst ranges):
// r0 fa->airport [0,kNA) | r1 af->flight [kNA,kNA+kNF)
// r2 ff->flight [kNA+kNF, kNA+2kNF) | r3 aa->airport [kNA+2kNF, kSEG)
constexpr int kSEG = 2 * kNA + 2 * kNF;           // 208000
constexpr int kScanBlocks = (kSEG + 1023) / 1024; // 204

typedef __attribute__((ext_vector_type(8))) short short8v;
typedef __attribute__((ext_vector_type(4))) float float4v;

__device__ __forceinline__ float b2f(unsigned short u) {
  union { unsigned int i; float f; } v;
  v.i = ((unsigned int)u) << 16;
  return v.f;
}
__device__ __forceinline__ unsigned short f2b(float f) {
  union { float f; unsigned int i; } v;
  v.f = f;
  unsigned int x = v.i;
  x += 0x7fffu + ((x >> 16) & 1u);  // round-to-nearest-even
  return (unsigned short)(x >> 16);
}

// ---------------------------------------------------------------------------
// Encoders: xout[rowoff+i] = xin[i] @ W + bias   (W [KIN][256]), bf16 out
// ---------------------------------------------------------------------------
template <int KIN>
__global__ __launch_bounds__(256) void k_encoder(
    const float* __restrict__ xin, const float* __restrict__ W,
    const float* __restrict__ bias, unsigned short* __restrict__ xout, int M,
    int rowoff) {
  __shared__ float xs[32][KIN];
  const int tid = threadIdx.x;
  const int r0 = blockIdx.x * 32;
  constexpr int TOT = 32 * KIN;
  for (int idx = tid * 4; idx < TOT; idx += 256 * 4) {
    const int rr = idx / KIN;
    const int kk = idx % KIN;
    *(float4*)&xs[rr][kk] = *(const float4*)&xin[(size_t)(r0 + rr) * KIN + kk];
  }
  __syncthreads();
  float acc[32];
#pragma unroll
  for (int i = 0; i < 32; ++i) acc[i] = 0.f;
  for (int k = 0; k < KIN; ++k) {
    const float wk = W[k * kH + tid];
#pragma unroll
    for (int i = 0; i < 32; ++i) acc[i] += xs[i][k] * wk;
  }
  const float bb = bias[tid];
#pragma unroll
  for (int i = 0; i < 32; ++i) {
    const int r = r0 + i;
    if (r < M) xout[(size_t)(rowoff + r) * kH + tid] = f2b(acc[i] + bb);
  }
}

// ---------------------------------------------------------------------------
// CSR build (all relations in one dispatch)
// ---------------------------------------------------------------------------
__device__ __forceinline__ void edge_decode(int i, const int* ei_fa,
                                            const int* ei_af, const int* ei_ff,
                                            const int* ei_aa, int& src,
                                            int& dstseg) {
  // relation ranges in concatenated edge id space
  if (i < kEFA) {
    src = ei_fa[i];                       // flight src (global id = local)
    dstseg = 0 + ei_fa[kEFA + i];         // r0 base 0
  } else if (i < kEFA + kEAF) {
    const int j = i - kEFA;
    src = kNF + ei_af[j];                 // airport src
    dstseg = kNA + ei_af[kEAF + j];       // r1 base kNA
  } else if (i < kEFA + kEAF + kEFF) {
    const int j = i - kEFA - kEAF;
    src = ei_ff[j];
    dstseg = kNA + kNF + ei_ff[kEFF + j]; // r2
  } else {
    const int j = i - kEFA - kEAF - kEFF;
    src = kNF + ei_aa[j];
    dstseg = kNA + 2 * kNF + ei_aa[kEAA + j];  // r3
  }
}

__global__ void k_count_all(const int* __restrict__ ei_fa,
                            const int* __restrict__ ei_af,
                            const int* __restrict__ ei_ff,
                            const int* __restrict__ ei_aa,
                            int* __restrict__ cnt) {
  const int i = blockIdx.x * 256 + threadIdx.x;
  if (i >= kETOT) return;
  int src, dstseg;
  edge_decode(i, ei_fa, ei_af, ei_ff, ei_aa, src, dstseg);
  atomicAdd(&cnt[dstseg], 1);
}

__global__ void k_scan1(const int* __restrict__ cnt, int* __restrict__ out,
                        int* __restrict__ bsum) {
  __shared__ int sh[256];
  const int tid = threadIdx.x;
  const int base = blockIdx.x * 1024 + tid * 4;
  int v[4];
#pragma unroll
  for (int j = 0; j < 4; ++j) v[j] = (base + j < kSEG) ? cnt[base + j] : 0;
  const int tsum = v[0] + v[1] + v[2] + v[3];
  sh[tid] = tsum;
  __syncthreads();
  for (int o = 1; o < 256; o <<= 1) {
    int t = (tid >= o) ? sh[tid - o] : 0;
    __syncthreads();
    sh[tid] += t;
    __syncthreads();
  }
  const int excl = sh[tid] - tsum;
  int run = excl;
#pragma unroll
  for (int j = 0; j < 4; ++j) {
    if (base + j < kSEG) out[base + j] = run;
    run += v[j];
  }
  if (tid == 255) bsum[blockIdx.x] = sh[255];
}

__global__ void k_scan2(const int* __restrict__ bsum, int* __restrict__ bpre) {
  __shared__ int sh[256];
  const int tid = threadIdx.x;
  const int v = (tid < kScanBlocks) ? bsum[tid] : 0;
  sh[tid] = v;
  __syncthreads();
  for (int o = 1; o < 256; o <<= 1) {
    int t = (tid >= o) ? sh[tid - o] : 0;
    __syncthreads();
    sh[tid] += t;
    __syncthreads();
  }
  if (tid < kScanBlocks) bpre[tid] = sh[tid] - v;
}

__global__ void k_scan3(int* __restrict__ off, int* __restrict__ cursor,
                        const int* __restrict__ bpre) {
  const int i = blockIdx.x * 256 + threadIdx.x;
  if (i < kSEG) {
    const int val = off[i] + bpre[i >> 10];
    off[i] = val;
    cursor[i] = val;
  }
  if (i == 0) off[kSEG] = kETOT;
}

__global__ void k_fill_all(const int* __restrict__ ei_fa,
                           const int* __restrict__ ei_af,
                           const int* __restrict__ ei_ff,
                           const int* __restrict__ ei_aa,
                           int* __restrict__ cursor, int* __restrict__ elist) {
  const int i = blockIdx.x * 256 + threadIdx.x;
  if (i >= kETOT) return;
  int src, dstseg;
  edge_decode(i, ei_fa, ei_af, ei_ff, ei_aa, src, dstseg);
  const int pos = atomicAdd(&cursor[dstseg], 1);
  elist[pos] = src;
}

__global__ void k_invdeg(const int* __restrict__ cnt,
                         float* __restrict__ invdeg) {
  const int i = blockIdx.x * 256 + threadIdx.x;
  if (i < kSEG) {
    const int c = cnt[i];
    invdeg[i] = 1.0f / (float)(c > 0 ? c : 1);
  }
}

// ---------------------------------------------------------------------------
// Stacked transposed B build (bf16):
//   BtF[n][k] = ([W_r1; W_r2; root])[k][n],  BtA likewise with {r0, r3}.
// ---------------------------------------------------------------------------
__global__ void k_build_Bt(const float* __restrict__ comp_l,
                           const float* __restrict__ basis_l,
                           const float* __restrict__ root_l,
                           unsigned short* __restrict__ BtF,
                           unsigned short* __restrict__ BtA) {
  const int idx = blockIdx.x * 256 + threadIdx.x;
  if (idx >= 2 * kK * kH) return;
  const int t = idx / (kK * kH);
  const int rem = idx % (kK * kH);
  const int n = rem / kK;     // 0..255 output col
  const int k = rem % kK;     // 0..767
  const int slot = k >> 8;    // 0,1,2
  const int wrow = k & 255;
  float val;
  if (slot == 2) {
    val = root_l[wrow * kH + n];
  } else {
    const int r = (t == 0) ? (slot == 0 ? 1 : 2) : (slot == 0 ? 0 : 3);
    const int io = wrow * kH + n;
    val = comp_l[r * kB + 0] * basis_l[0 * kH * kH + io] +
          comp_l[r * kB + 1] * basis_l[1 * kH * kH + io] +
          comp_l[r * kB + 2] * basis_l[2 * kH * kH + io];
  }
  (t == 0 ? BtF : BtA)[(size_t)n * kK + k] = f2b(val);
}

// ---------------------------------------------------------------------------
// Gather-mean: Aagg[d][slot*256..] = mean_{src in CSR[d]} x[src]  (bf16)
// 32 lanes per destination (2 dsts per wave); blockIdx.y = slot (0/1).
// ---------------------------------------------------------------------------
__global__ __launch_bounds__(256) void k_gather2(
    const unsigned short* __restrict__ x, unsigned short* __restrict__ Aagg,
    const int* __restrict__ off, const int* __restrict__ elist,
    const float* __restrict__ invdeg, int segbase0, int segbase1, int c0,
    int nrows) {
  const int half = threadIdx.x >> 5;  // 0..7
  const int lane = threadIdx.x & 31;
  const int d = blockIdx.x * 8 + half;
  const int slot = blockIdx.y;
  if (d >= nrows) return;
  const int s = (slot == 0 ? segbase0 : segbase1) + c0 + d;
  const int lo = off[s], hi = off[s + 1];
  const float iv = invdeg[s];
  float a0 = 0.f, a1 = 0.f, a2 = 0.f, a3 = 0.f;
  float a4 = 0.f, a5 = 0.f, a6 = 0.f, a7 = 0.f;
  const unsigned short* xl = x + lane * 8;
  int e = lo;
  for (; e + 1 < hi; e += 2) {
    const int s0 = elist[e];
    const int s1 = elist[e + 1];
    const uint4 v0 = *(const uint4*)(xl + (size_t)s0 * kH);
    const uint4 v1 = *(const uint4*)(xl + (size_t)s1 * kH);
    a0 += b2f((unsigned short)v0.x) + b2f((unsigned short)v1.x);
    a1 += b2f((unsigned short)(v0.x >> 16)) + b2f((unsigned short)(v1.x >> 16));
    a2 += b2f((unsigned short)v0.y) + b2f((unsigned short)v1.y);
    a3 += b2f((unsigned short)(v0.y >> 16)) + b2f((unsigned short)(v1.y >> 16));
    a4 += b2f((unsigned short)v0.z) + b2f((unsigned short)v1.z);
    a5 += b2f((unsigned short)(v0.z >> 16)) + b2f((unsigned short)(v1.z >> 16));
    a6 += b2f((unsigned short)v0.w) + b2f((unsigned short)v1.w);
    a7 += b2f((unsigned short)(v0.w >> 16)) + b2f((unsigned short)(v1.w >> 16));
  }
  if (e < hi) {
    const int s0 = elist[e];
    const uint4 v0 = *(const uint4*)(xl + (size_t)s0 * kH);
    a0 += b2f((unsigned short)v0.x);
    a1 += b2f((unsigned short)(v0.x >> 16));
    a2 += b2f((unsigned short)v0.y);
    a3 += b2f((unsigned short)(v0.y >> 16));
    a4 += b2f((unsigned short)v0.z);
    a5 += b2f((unsigned short)(v0.z >> 16));
    a6 += b2f((unsigned short)v0.w);
    a7 += b2f((unsigned short)(v0.w >> 16));
  }
  uint4 o;
  o.x = (unsigned int)f2b(a0 * iv) | ((unsigned int)f2b(a1 * iv) << 16);
  o.y = (unsigned int)f2b(a2 * iv) | ((unsigned int)f2b(a3 * iv) << 16);
  o.z = (unsigned int)f2b(a4 * iv) | ((unsigned int)f2b(a5 * iv) << 16);
  o.w = (unsigned int)f2b(a6 * iv) | ((unsigned int)f2b(a7 * iv) << 16);
  *(uint4*)&Aagg[(size_t)d * kKA + slot * kH + lane * 8] = o;
}

// ---------------------------------------------------------------------------
// MFMA GEMM: C[M][256] = [Aagg | x] @ Bt^T + bias, bf16 out.
// Aagg [M][512] bf16, x slot read from xbuf rows (xrow0+...), Bt [256][768].
// Block: 256 threads (4 waves), tile 64 rows x 256 cols; wave w owns cols
// w*64 (4 m-frags x 4 n-frags of 16x16). A tile staged in LDS (stride 40).
// ---------------------------------------------------------------------------
__global__ __launch_bounds__(256) void k_gemm_mfma(
    const unsigned short* __restrict__ Aagg,
    const unsigned short* __restrict__ xbuf,
    const unsigned short* __restrict__ Bt, unsigned short* __restrict__ C,
    const float* __restrict__ bias, int M, int xrow0) {
  __shared__ unsigned short As[64][40];
  const int tid = threadIdx.x;
  const int wave = tid >> 6;
  const int lane = tid & 63;
  const int brow = blockIdx.x * 64;
  const int ncol0 = wave * 64;

  const int lrow = tid >> 2;      // 0..63 staging row
  const int lk8 = (tid & 3) * 8;  // 0,8,16,24 (bf16 units)

  const int fr = lane & 15;
  const int fq = lane >> 4;

  const bool arow_ok = (brow + lrow) < M;
  const unsigned short* Arow = Aagg + (size_t)(brow + lrow) * kKA + lk8;
  const unsigned short* Xrow = xbuf + (size_t)(xrow0 + brow + lrow) * kH + lk8;
  const unsigned short* Bt0 = Bt + (size_t)(ncol0 + fr) * kK + fq * 8;

  float4v acc[4][4];
#pragma unroll
  for (int mi = 0; mi < 4; ++mi)
#pragma unroll
    for (int ni = 0; ni < 4; ++ni) acc[mi][ni] = (float4v)(0.f);

  for (int kt = 0; kt < kK; kt += 32) {
    uint4 av = make_uint4(0, 0, 0, 0);
    if (arow_ok)
      av = (kt < kKA) ? *(const uint4*)(Arow + kt)
                      : *(const uint4*)(Xrow + (kt - kKA));
    short8v bfrag[4];
#pragma unroll
    for (int ni = 0; ni < 4; ++ni)
      bfrag[ni] = *(const short8v*)(Bt0 + (size_t)ni * 16 * kK + kt);
    __syncthreads();  // previous iter's LDS reads done
    *(uint4*)&As[lrow][lk8] = av;
    __syncthreads();
    short8v afrag[4];
#pragma unroll
    for (int mi = 0; mi < 4; ++mi)
      afrag[mi] = *(const short8v*)&As[mi * 16 + fr][fq * 8];
#pragma unroll
    for (int mi = 0; mi < 4; ++mi)
#pragma unroll
      for (int ni = 0; ni < 4; ++ni)
        acc[mi][ni] = __builtin_amdgcn_mfma_f32_16x16x32_bf16(
            afrag[mi], bfrag[ni], acc[mi][ni], 0, 0, 0);
  }

  // epilogue: C row = brow + mi*16 + fq*4 + reg, col = ncol0 + ni*16 + fr
#pragma unroll
  for (int ni = 0; ni < 4; ++ni) {
    const int col = ncol0 + ni * 16 + fr;
    const float bb = bias[col];
#pragma unroll
    for (int mi = 0; mi < 4; ++mi) {
      const int row0 = brow + mi * 16 + fq * 4;
#pragma unroll
      for (int reg = 0; reg < 4; ++reg) {
        const int r = row0 + reg;
        if (r < M) C[(size_t)r * kH + col] = f2b(acc[mi][ni][reg] + bb);
      }
    }
  }
}

// ---------------------------------------------------------------------------
// x = leaky(LN(h)) + x   (bf16 io, fp32 math). One wave per row.
// ---------------------------------------------------------------------------
__global__ __launch_bounds__(256) void k_ln_res(
    const unsigned short* __restrict__ h, unsigned short* __restrict__ x,
    const float* __restrict__ gamma, const float* __restrict__ beta) {
  const int wave = threadIdx.x >> 6;
  const int lane = threadIdx.x & 63;
  const int row = blockIdx.x * 4 + wave;
  if (row >= kN) return;
  const ushort4 hv = *(const ushort4*)&h[(size_t)row * kH + (lane << 2)];
  float v0 = b2f(hv.x), v1 = b2f(hv.y), v2 = b2f(hv.z), v3 = b2f(hv.w);
  float s = v0 + v1 + v2 + v3;
  float ss = v0 * v0 + v1 * v1 + v2 * v2 + v3 * v3;
#pragma unroll
  for (int o = 1; o < 64; o <<= 1) {
    s += __shfl_xor(s, o);
    ss += __shfl_xor(ss, o);
  }
  const float mu = s * (1.f / kH);
  const float var = ss * (1.f / kH) - mu * mu;
  const float rs = rsqrtf(var + 1e-5f);
  const float4 g = *(const float4*)&gamma[lane << 2];
  const float4 b = *(const float4*)&beta[lane << 2];
  float t0 = (v0 - mu) * rs * g.x + b.x;
  float t1 = (v1 - mu) * rs * g.y + b.y;
  float t2 = (v2 - mu) * rs * g.z + b.z;
  float t3 = (v3 - mu) * rs * g.w + b.w;
  t0 = t0 > 0.f ? t0 : 0.1f * t0;
  t1 = t1 > 0.f ? t1 : 0.1f * t1;
  t2 = t2 > 0.f ? t2 : 0.1f * t2;
  t3 = t3 > 0.f ? t3 : 0.1f * t3;
  const ushort4 xv = *(const ushort4*)&x[(size_t)row * kH + (lane << 2)];
  ushort4 o;
  o.x = f2b(b2f(xv.x) + t0);
  o.y = f2b(b2f(xv.y) + t1);
  o.z = f2b(b2f(xv.z) + t2);
  o.w = f2b(b2f(xv.w) + t3);
  *(ushort4*)&x[(size_t)row * kH + (lane << 2)] = o;
}

// ---------------------------------------------------------------------------
// Readout: out[n] = dot(x[n], ro_w) + ro_b  (flight rows), fp32 out.
// ---------------------------------------------------------------------------
__global__ __launch_bounds__(256) void k_readout(
    const unsigned short* __restrict__ x, const float* __restrict__ w,
    const float* __restrict__ b, float* __restrict__ out) {
  const int wave = threadIdx.x >> 6;
  const int lane = threadIdx.x & 63;
  const int row = blockIdx.x * 4 + wave;
  if (row >= kNF) return;
  const ushort4 v = *(const ushort4*)&x[(size_t)row * kH + (lane << 2)];
  const float4 wv = *(const float4*)&w[lane << 2];
  float s = b2f(v.x) * wv.x + b2f(v.y) * wv.y + b2f(v.z) * wv.z +
            b2f(v.w) * wv.w;
#pragma unroll
  for (int o = 1; o < 64; o <<= 1) s += __shfl_xor(s, o);
  if (lane == 0) out[row] = s + b[0];
}

}  // namespace

// ---------------------------------------------------------------------------
extern "C" void kernel_launch(void* const* d_in, const int* in_sizes, int n_in,
                              void* d_out, int out_size, void* d_ws,
                              size_t ws_size, hipStream_t stream) {
  const float* x_flight = (const float*)d_in[0];
  const float* x_airport = (const float*)d_in[1];
  const float* enc_w_f = (const float*)d_in[2];
  const float* enc_b_f = (const float*)d_in[3];
  const float* enc_w_a = (const float*)d_in[4];
  const float* enc_b_a = (const float*)d_in[5];
  const float* basis = (const float*)d_in[6];
  const float* comp = (const float*)d_in[7];
  const float* root = (const float*)d_in[8];
  const float* conv_bias = (const float*)d_in[9];
  const float* ln_gamma = (const float*)d_in[10];
  const float* ln_beta = (const float*)d_in[11];
  const float* ro_w = (const float*)d_in[12];
  const float* ro_b = (const float*)d_in[13];
  const int* ei_fa = (const int*)d_in[14];
  const int* ei_af = (const int*)d_in[15];
  const int* ei_ff = (const int*)d_in[16];
  const int* ei_aa = (const int*)d_in[17];
  float* out = (float*)d_out;

  // workspace carve (fixed buffers first, then adaptive A-chunk)
  char* base = (char*)d_ws;
  size_t off_b = 0;
  auto carve = [&](size_t bytes) -> char* {
    char* p = base + off_b;
    off_b += (bytes + 255) & ~(size_t)255;
    return p;
  };
  unsigned short* xbuf = (unsigned short*)carve((size_t)kN * kH * 2);
  unsigned short* hbuf = (unsigned short*)carve((size_t)kN * kH * 2);
  unsigned short* BtF = (unsigned short*)carve((size_t)kK * kH * 2);
  unsigned short* BtA = (unsigned short*)carve((size_t)kK * kH * 2);
  int* cnt = (int*)carve((size_t)kSEG * 4);
  int* offs = (int*)carve((size_t)(kSEG + 1) * 4);
  int* cursor = (int*)carve((size_t)kSEG * 4);
  int* elist = (int*)carve((size_t)kETOT * 4);
  int* bsum = (int*)carve((size_t)kScanBlocks * 4);
  int* bpre = (int*)carve((size_t)kScanBlocks * 4);
  float* invdeg = (float*)carve((size_t)kSEG * 4);
  // adaptive chunk rows (multiple of 64, cap 32768)
  size_t rem = (ws_size > off_b + 4096) ? (ws_size - off_b - 4096) : 0;
  int CH = (int)(rem / ((size_t)kKA * 2));
  if (CH > 32768) CH = 32768;
  CH &= ~63;
  if (CH < 64) CH = 64;  // (ws_size too small to function; best effort)
  unsigned short* Achunk = (unsigned short*)carve((size_t)CH * kKA * 2);

  // --- encoders ---
  k_encoder<32><<<kNF / 32, 256, 0, stream>>>(x_flight, enc_w_f, enc_b_f, xbuf,
                                              kNF, 0);
  k_encoder<16><<<kNA / 32, 256, 0, stream>>>(x_airport, enc_w_a, enc_b_a, xbuf,
                                              kNA, kNF);

  // --- CSR build ---
  hipMemsetAsync(cnt, 0, (size_t)kSEG * 4, stream);
  const int b0 = 0, b1 = kNA, b2 = kNA + kNF, b3 = kNA + 2 * kNF;
  k_count_all<<<(kETOT + 255) / 256, 256, 0, stream>>>(ei_fa, ei_af, ei_ff,
                                                       ei_aa, cnt);
  k_scan1<<<kScanBlocks, 256, 0, stream>>>(cnt, offs, bsum);
  k_scan2<<<1, 256, 0, stream>>>(bsum, bpre);
  k_scan3<<<(kSEG + 255) / 256, 256, 0, stream>>>(offs, cursor, bpre);
  k_invdeg<<<(kSEG + 255) / 256, 256, 0, stream>>>(cnt, invdeg);
  k_fill_all<<<(kETOT + 255) / 256, 256, 0, stream>>>(ei_fa, ei_af, ei_ff,
                                                      ei_aa, cursor, elist);

  // --- layers ---
  for (int l = 0; l < kL; ++l) {
    const float* comp_l = comp + (size_t)l * 4 * kB;
    const float* basis_l = basis + (size_t)l * kB * kH * kH;
    const float* root_l = root + (size_t)l * kH * kH;
    const float* bias_l = conv_bias + (size_t)l * kH;
    const float* gamma_l = ln_gamma + (size_t)l * kH;
    const float* beta_l = ln_beta + (size_t)l * kH;

    k_build_Bt<<<(2 * kK * kH + 255) / 256, 256, 0, stream>>>(comp_l, basis_l,
                                                              root_l, BtF, BtA);

    // flight rows: slots {r1(af), r2(ff)}, x rows [0, kNF)
    for (int c0 = 0; c0 < kNF; c0 += CH) {
      const int rows = (kNF - c0 < CH) ? (kNF - c0) : CH;
      dim3 gg((rows + 7) / 8, 2);
      k_gather2<<<gg, 256, 0, stream>>>(xbuf, Achunk, offs, elist, invdeg, b1,
                                        b2, c0, rows);
      dim3 g((rows + 63) / 64);
      k_gemm_mfma<<<g, 256, 0, stream>>>(Achunk, xbuf, BtF,
                                         hbuf + (size_t)c0 * kH, bias_l, rows,
                                         c0);
    }
    // airport rows: slots {r0(fa), r3(aa)}, x rows [kNF, kN)
    for (int c0 = 0; c0 < kNA; c0 += CH) {
      const int rows = (kNA - c0 < CH) ? (kNA - c0) : CH;
      dim3 gg((rows + 7) / 8, 2);
      k_gather2<<<gg, 256, 0, stream>>>(xbuf, Achunk, offs, elist, invdeg, b0,
                                        b3, c0, rows);
      dim3 g((rows + 63) / 64);
      k_gemm_mfma<<<g, 256, 0, stream>>>(Achunk, xbuf, BtA,
                                         hbuf + (size_t)(kNF + c0) * kH, bias_l,
                                         rows, kNF + c0);
    }

    k_ln_res<<<(kN + 3) / 4, 256, 0, stream>>>(hbuf, xbuf, gamma_l, beta_l);
  }

  // --- readout ---
  k_readout<<<(kNF + 3) / 4, 256, 0, stream>>>(xbuf, ro_w, ro_b, out);
}